// Round 1
// baseline (215.251 us; speedup 1.0000x reference)
//
#include <hip/hip_runtime.h>

// ---------------------------------------------------------------------------
// WindowAttention fused kernel for MI355X (gfx950)
// B=1024 windows, N=64 tokens, C=256, H=8 heads, hd=32
// ---------------------------------------------------------------------------

typedef __attribute__((ext_vector_type(8))) __bf16 bf16x8;
typedef __attribute__((ext_vector_type(4))) float f32x4;
typedef __attribute__((ext_vector_type(4))) unsigned short u16x4;

#define LOFF_QS 16384   // Q tile (later V^T) , elems (ushort)
#define LOFF_KS 32768   // K tile (later O)
#define LOFF_PS 49152   // P (8 heads x 64 x 64)

__device__ __forceinline__ unsigned short f2bf(float f) {
  unsigned int u = __float_as_uint(f);
  u += 0x7FFFu + ((u >> 16) & 1u);          // round-to-nearest-even
  return (unsigned short)(u >> 16);
}

// swizzles: XOR row bits into 16B-slot bits so 16-lane column reads spread banks
__device__ __forceinline__ int swz256(int row, int col) {   // 256-elem (512B) rows
  return row * 256 + (col ^ ((row & 31) << 3));
}
__device__ __forceinline__ int swz64(int row, int col) {    // 64-elem (128B) rows
  return row * 64 + (col ^ ((row & 7) << 3));
}

// ---------------- pre-kernel 1: pack weights into B-frag layout -------------
// packed[w][cb][kc][lane][i] = W_w[cb*16 + (lane&15)][kc*32 + (lane>>4)*8 + i]
__global__ void pack_weights(const float* __restrict__ W0, const float* __restrict__ W1,
                             const float* __restrict__ W2, const float* __restrict__ W3,
                             const float* __restrict__ W4, const float* __restrict__ W5,
                             const float* __restrict__ W6, const float* __restrict__ W7,
                             unsigned short* __restrict__ pk) {
  int t = blockIdx.x * 256 + threadIdx.x;   // 65536 threads
  int wsel = t >> 13;
  int rem  = t & 8191;
  int cb   = rem >> 9;
  int kc   = (rem >> 6) & 7;
  int l    = rem & 63;
  const float* W = (wsel == 0) ? W0 : (wsel == 1) ? W1 : (wsel == 2) ? W2 : (wsel == 3) ? W3
                 : (wsel == 4) ? W4 : (wsel == 5) ? W5 : (wsel == 6) ? W6 : W7;
  int row = cb * 16 + (l & 15);
  int col = kc * 32 + ((l >> 4) << 3);
  const float* src = W + row * 256 + col;
  unsigned short* dst = pk + (size_t)t * 8;
#pragma unroll
  for (int i = 0; i < 8; ++i) dst[i] = f2bf(src[i]);
}

// ---------------- pre-kernel 2: bm[w][h][i][j] = mask + rel_bias ------------
__global__ void make_bm(const float* __restrict__ mask, const float* __restrict__ btab,
                        const int* __restrict__ ridx, float* __restrict__ bm) {
  int t = blockIdx.x * 256 + threadIdx.x;   // 2,097,152 threads
  int j = t & 63;
  int i = (t >> 6) & 63;
  int h = (t >> 12) & 7;
  int wi = t >> 15;
  bm[t] = mask[(wi * 64 + i) * 64 + j] + btab[ridx[i * 64 + j] * 8 + h];
}

// ---------------- device helpers -------------------------------------------
// stage one [64][256] fp32 input into bf16 LDS tile (swizzled)
__device__ __forceinline__ void stage_x(unsigned short* XS, const float* __restrict__ X,
                                        int b, int tid) {
  const float4* src = reinterpret_cast<const float4*>(X + (size_t)b * 16384);
#pragma unroll
  for (int it = 0; it < 8; ++it) {
    int f = it * 512 + tid;               // float4 index 0..4095
    float4 v = src[f];
    int row = f >> 6;
    int col = (f & 63) << 2;
    u16x4 p;
    p[0] = f2bf(v.x); p[1] = f2bf(v.y); p[2] = f2bf(v.z); p[3] = f2bf(v.w);
    *reinterpret_cast<u16x4*>(XS + swz256(row, col)) = p;
  }
}

// GEMM: acc[4][2] = (A[64x256] @ W^T)[:, 32w:32w+32]; A from LDS, W packed in ws
__device__ __forceinline__ void proj_core(const unsigned short* __restrict__ aTile,
                                          const unsigned short* __restrict__ pw,
                                          const float* __restrict__ bias, float scale,
                                          int lane, int w, f32x4 acc[4][2]) {
  const int r16 = lane & 15, c4 = lane >> 4;
  f32x4 z = {0.f, 0.f, 0.f, 0.f};
#pragma unroll
  for (int mf = 0; mf < 4; ++mf)
#pragma unroll
    for (int nf = 0; nf < 2; ++nf) acc[mf][nf] = z;
#pragma unroll
  for (int kc = 0; kc < 8; ++kc) {
    bf16x8 a[4];
#pragma unroll
    for (int mf = 0; mf < 4; ++mf) {
      int row = mf * 16 + r16;
      int col = kc * 32 + (c4 << 3);
      a[mf] = *reinterpret_cast<const bf16x8*>(aTile + swz256(row, col));
    }
    bf16x8 bb[2];
#pragma unroll
    for (int nf = 0; nf < 2; ++nf)
      bb[nf] = *reinterpret_cast<const bf16x8*>(pw + ((((2 * w + nf) * 8 + kc) * 64 + lane) << 3));
#pragma unroll
    for (int mf = 0; mf < 4; ++mf)
#pragma unroll
      for (int nf = 0; nf < 2; ++nf)
        acc[mf][nf] = __builtin_amdgcn_mfma_f32_16x16x32_bf16(a[mf], bb[nf], acc[mf][nf], 0, 0, 0);
  }
  float b0 = bias[w * 32 + r16];
  float b1 = bias[w * 32 + 16 + r16];
#pragma unroll
  for (int mf = 0; mf < 4; ++mf)
#pragma unroll
    for (int r = 0; r < 4; ++r) {
      acc[mf][0][r] = (acc[mf][0][r] + b0) * scale;
      acc[mf][1][r] = (acc[mf][1][r] + b1) * scale;
    }
}

// store C-frags row-major bf16 [64][256] (swz256)
__device__ __forceinline__ void store_rm_bf16(unsigned short* dst, const f32x4 acc[4][2],
                                              int lane, int w) {
  const int r16 = lane & 15, c4 = lane >> 4;
#pragma unroll
  for (int mf = 0; mf < 4; ++mf)
#pragma unroll
    for (int nf = 0; nf < 2; ++nf)
#pragma unroll
      for (int r = 0; r < 4; ++r) {
        int row = mf * 16 + c4 * 4 + r;
        int col = w * 32 + nf * 16 + r16;
        dst[swz256(row, col)] = f2bf(acc[mf][nf][r]);
      }
}

// store C-frags transposed into V^T [256 dims][64 tokens] bf16 (swz64)
__device__ __forceinline__ void store_tr_bf16(unsigned short* dst, const f32x4 acc[4][2],
                                              int lane, int w) {
  const int r16 = lane & 15, c4 = lane >> 4;
#pragma unroll
  for (int mf = 0; mf < 4; ++mf)
#pragma unroll
    for (int nf = 0; nf < 2; ++nf)
#pragma unroll
      for (int r = 0; r < 4; ++r) {
        int vrow = w * 32 + nf * 16 + r16;       // dim
        int vcol = mf * 16 + c4 * 4 + r;          // token
        dst[swz64(vrow, vcol)] = f2bf(acc[mf][nf][r]);
      }
}

// store C-frags to global fp32 [64][256]
__device__ __forceinline__ void store_gl_f32(float* __restrict__ dst, const f32x4 acc[4][2],
                                             int lane, int w) {
  const int r16 = lane & 15, c4 = lane >> 4;
#pragma unroll
  for (int mf = 0; mf < 4; ++mf)
#pragma unroll
    for (int nf = 0; nf < 2; ++nf)
#pragma unroll
      for (int r = 0; r < 4; ++r) {
        int row = mf * 16 + c4 * 4 + r;
        int col = w * 32 + nf * 16 + r16;
        dst[row * 256 + col] = acc[mf][nf][r];
      }
}

// attention for head w: S = Q_h K_h^T + bm, softmax rows, P -> LDS (bf16)
__device__ __forceinline__ void attn_core(const unsigned short* __restrict__ sm,
                                          const float* __restrict__ bmw,
                                          int lane, int w, unsigned short* Ps) {
  const int r16 = lane & 15, c4 = lane >> 4;
  const unsigned short* Qs = sm + LOFF_QS;
  const unsigned short* Ks = sm + LOFF_KS;
  bf16x8 aq[4], bk4[4];
#pragma unroll
  for (int mf = 0; mf < 4; ++mf)
    aq[mf] = *reinterpret_cast<const bf16x8*>(Qs + swz256(mf * 16 + r16, w * 32 + (c4 << 3)));
#pragma unroll
  for (int nf = 0; nf < 4; ++nf)
    bk4[nf] = *reinterpret_cast<const bf16x8*>(Ks + swz256(nf * 16 + r16, w * 32 + (c4 << 3)));
  f32x4 z = {0.f, 0.f, 0.f, 0.f};
  f32x4 s[4][4];
#pragma unroll
  for (int mf = 0; mf < 4; ++mf)
#pragma unroll
    for (int nf = 0; nf < 4; ++nf)
      s[mf][nf] = __builtin_amdgcn_mfma_f32_16x16x32_bf16(aq[mf], bk4[nf], z, 0, 0, 0);
#pragma unroll
  for (int mf = 0; mf < 4; ++mf)
#pragma unroll
    for (int r = 0; r < 4; ++r) {
      int row = mf * 16 + c4 * 4 + r;
      const float* bp = bmw + row * 64 + r16;
      float v0 = s[mf][0][r] + bp[0];
      float v1 = s[mf][1][r] + bp[16];
      float v2 = s[mf][2][r] + bp[32];
      float v3 = s[mf][3][r] + bp[48];
      float m = fmaxf(fmaxf(v0, v1), fmaxf(v2, v3));
      m = fmaxf(m, __shfl_xor(m, 1));
      m = fmaxf(m, __shfl_xor(m, 2));
      m = fmaxf(m, __shfl_xor(m, 4));
      m = fmaxf(m, __shfl_xor(m, 8));
      float e0 = __expf(v0 - m), e1 = __expf(v1 - m);
      float e2 = __expf(v2 - m), e3 = __expf(v3 - m);
      float sum = e0 + e1 + e2 + e3;
      sum += __shfl_xor(sum, 1);
      sum += __shfl_xor(sum, 2);
      sum += __shfl_xor(sum, 4);
      sum += __shfl_xor(sum, 8);
      float inv = 1.0f / sum;
      Ps[swz64(row, r16)]      = f2bf(e0 * inv);
      Ps[swz64(row, r16 + 16)] = f2bf(e1 * inv);
      Ps[swz64(row, r16 + 32)] = f2bf(e2 * inv);
      Ps[swz64(row, r16 + 48)] = f2bf(e3 * inv);
    }
}

// O_h = P_h @ V_h  (A from P LDS, B from V^T LDS)
__device__ __forceinline__ void pv_core(const unsigned short* __restrict__ Ps,
                                        const unsigned short* __restrict__ Vt,
                                        int lane, int w, f32x4 o[4][2]) {
  const int r16 = lane & 15, c4 = lane >> 4;
  f32x4 z = {0.f, 0.f, 0.f, 0.f};
#pragma unroll
  for (int mf = 0; mf < 4; ++mf)
#pragma unroll
    for (int nf = 0; nf < 2; ++nf) o[mf][nf] = z;
#pragma unroll
  for (int kc = 0; kc < 2; ++kc) {
    bf16x8 a[4];
#pragma unroll
    for (int mf = 0; mf < 4; ++mf)
      a[mf] = *reinterpret_cast<const bf16x8*>(Ps + swz64(mf * 16 + r16, kc * 32 + (c4 << 3)));
    bf16x8 bb[2];
#pragma unroll
    for (int nf = 0; nf < 2; ++nf)
      bb[nf] = *reinterpret_cast<const bf16x8*>(Vt + swz64(w * 32 + nf * 16 + r16, kc * 32 + (c4 << 3)));
#pragma unroll
    for (int mf = 0; mf < 4; ++mf)
#pragma unroll
      for (int nf = 0; nf < 2; ++nf)
        o[mf][nf] = __builtin_amdgcn_mfma_f32_16x16x32_bf16(a[mf], bb[nf], o[mf][nf], 0, 0, 0);
  }
}

// ---------------- main fused kernel: one block per window -------------------
__global__ __launch_bounds__(512, 2) void win_attn(
    const float* __restrict__ gq, const float* __restrict__ gk, const float* __restrict__ gv,
    const float* __restrict__ gsc, const float* __restrict__ gsh,
    const unsigned short* __restrict__ pk,
    const float* __restrict__ b_q, const float* __restrict__ b_k, const float* __restrict__ b_v,
    const float* __restrict__ b_vs, const float* __restrict__ b_vh,
    const float* __restrict__ b_px, const float* __restrict__ b_ps, const float* __restrict__ b_ph,
    const float* __restrict__ bm, float* __restrict__ out) {
  __shared__ __align__(16) unsigned short sm[81920];   // 160 KiB exactly
  const int b    = blockIdx.x;
  const int tid  = threadIdx.x;
  const int lane = tid & 63;
  const int w    = tid >> 6;                            // wave id == head id

  unsigned short* XS = sm;
  unsigned short* QS = sm + LOFF_QS;                    // Q, later V^T
  unsigned short* KS = sm + LOFF_KS;                    // K, later O
  unsigned short* PS = sm + LOFF_PS + w * 4096;         // this head's P

  f32x4 acc[4][2];

  // A: stage Xq
  stage_x(XS, gq, b, tid);
  __syncthreads();
  // B: Q = (Xq Wq^T + bq) * scale
  proj_core(XS, pk, b_q, 0.17677669529663687f, lane, w, acc);
  store_rm_bf16(QS, acc, lane, w);
  __syncthreads();
  // C: stage Xk
  stage_x(XS, gk, b, tid);
  __syncthreads();
  // D: K
  proj_core(XS, pk + 65536, b_k, 1.0f, lane, w, acc);
  store_rm_bf16(KS, acc, lane, w);
  __syncthreads();
  // E: stage Xv  ||  attention (S, softmax, P)
  stage_x(XS, gv, b, tid);
  attn_core(sm, bm + (size_t)(((b & 63) * 8 + w) << 12), lane, w, PS);
  __syncthreads();
  // F: V -> V^T (in QS space)
  proj_core(XS, pk + 2 * 65536, b_v, 1.0f, lane, w, acc);
  store_tr_bf16(QS, acc, lane, w);
  __syncthreads();
  // G: stage Xscale || O_x = P V  (into KS space)
  stage_x(XS, gsc, b, tid);
  {
    f32x4 o[4][2];
    pv_core(PS, QS, lane, w, o);
    store_rm_bf16(KS, o, lane, w);
  }
  __syncthreads();
  // H: x_out = O_x Wpx^T + bpx  ||  V_scale -> V^T
  proj_core(KS, pk + 5 * 65536, b_px, 1.0f, lane, w, acc);
  store_gl_f32(out + (size_t)b * 16384, acc, lane, w);
  proj_core(XS, pk + 3 * 65536, b_vs, 1.0f, lane, w, acc);
  store_tr_bf16(QS, acc, lane, w);
  __syncthreads();
  // I: stage Xshift || O_s = P V_scale
  stage_x(XS, gsh, b, tid);
  {
    f32x4 o[4][2];
    pv_core(PS, QS, lane, w, o);
    store_rm_bf16(KS, o, lane, w);
  }
  __syncthreads();
  // J: scale_out  ||  V_shift -> V^T
  proj_core(KS, pk + 6 * 65536, b_ps, 1.0f, lane, w, acc);
  store_gl_f32(out + 16777216 + (size_t)b * 16384, acc, lane, w);
  proj_core(XS, pk + 4 * 65536, b_vh, 1.0f, lane, w, acc);
  store_tr_bf16(QS, acc, lane, w);
  __syncthreads();
  // K: O_h = P V_shift
  {
    f32x4 o[4][2];
    pv_core(PS, QS, lane, w, o);
    store_rm_bf16(KS, o, lane, w);
  }
  __syncthreads();
  // L: shift_out
  proj_core(KS, pk + 7 * 65536, b_ph, 1.0f, lane, w, acc);
  store_gl_f32(out + 33554432 + (size_t)b * 16384, acc, lane, w);
}

// ---------------------------------------------------------------------------
extern "C" void kernel_launch(void* const* d_in, const int* in_sizes, int n_in,
                              void* d_out, int out_size, void* d_ws, size_t ws_size,
                              hipStream_t stream) {
  const float* Xq   = (const float*)d_in[0];
  const float* Xk   = (const float*)d_in[1];
  const float* Xv   = (const float*)d_in[2];
  const float* Xsc  = (const float*)d_in[3];
  const float* Xsh  = (const float*)d_in[4];
  const float* mask = (const float*)d_in[5];
  const float* Wq   = (const float*)d_in[6];  const float* bq  = (const float*)d_in[7];
  const float* Wk   = (const float*)d_in[8];  const float* bk  = (const float*)d_in[9];
  const float* Wv   = (const float*)d_in[10]; const float* bv  = (const float*)d_in[11];
  const float* Wvs  = (const float*)d_in[12]; const float* bvs = (const float*)d_in[13];
  const float* Wvh  = (const float*)d_in[14]; const float* bvh = (const float*)d_in[15];
  const float* Wpx  = (const float*)d_in[16]; const float* bpx = (const float*)d_in[17];
  const float* Wps  = (const float*)d_in[18]; const float* bps = (const float*)d_in[19];
  const float* Wph  = (const float*)d_in[20]; const float* bph = (const float*)d_in[21];
  const float* btab = (const float*)d_in[22];
  const int*   ridx = (const int*)d_in[23];

  unsigned short* pk = (unsigned short*)d_ws;                 // 8 x 65536 bf16 = 1 MB
  float* bm = (float*)((char*)d_ws + (size_t)8 * 65536 * 2);  // 2M floats = 8 MB

  pack_weights<<<256, 256, 0, stream>>>(Wq, Wk, Wv, Wvs, Wvh, Wpx, Wps, Wph, pk);
  make_bm<<<8192, 256, 0, stream>>>(mask, btab, ridx, bm);
  win_attn<<<1024, 512, 0, stream>>>(Xq, Xk, Xv, Xsc, Xsh, pk,
                                     bq, bk, bv, bvs, bvh, bpx, bps, bph,
                                     bm, (float*)d_out);
}